// Round 11
// baseline (380.088 us; speedup 1.0000x reference)
//
#include <hip/hip_runtime.h>
#include <math.h>

// MPNN forward. Round 16:
//  - REVERT R15's k_sum split (350us: extra launch + m round-trip lost more
//    than staging parallelism won). k_gru back to R13 in-kernel segment sum.
//  - k_msg_mfma: R13 shape (256thr, 2 M-tiles, 2512 waves, rolling B
//    prefetch) + R14's VALIDATED numerics: A pre-split hi/lo ONCE in the
//    prologue, per-ks U = A.B via zero-C MFMA chain, acc += q*U with
//    per-row q from transposed ehs_t broadcast float4 (R14 passed at
//    absmax 4.88e-4). Bias steps (ks>=128) MFMA directly into acc.
//    VALU per ks ~106 -> ~50 (kills in-loop split8 + q-muls); R14's
//    failure was ONLY the 128-thr wave-count halving, not these edits.
//  - R13: launch fusion (prep_count/prep_scan/fill), rolling B prefetch.
//  - R11: dst-sorted edges, plain-store msgbuf (no atomics).
//  - R10: reg-resident A, direct-L2 B, no in-loop barriers.
//  - Rounds 1-9: K-split edge MFMA, fused GRU MFMA, split-bf16 hi/lo MFMA,
//    Bfat/Wg pre-pack, 256-thr set2set, parallel scans.

#define Nn 10000
#define Ee 20000
#define Bb 400
#define KSTEPS 130   // 128 (q,d) steps + 2 bias steps (K = 4160)
#define S2S_CHUNK 1024

#define FILL_A (Nn * 64)              // in_linear outputs
#define FILL_B (KSTEPS * 4096)        // Bfat elements
#define FILL_C (4 * 2 * 16 * 64 * 8)  // Wg elements

typedef __attribute__((ext_vector_type(8))) short bf16x8_t;
typedef __attribute__((ext_vector_type(4))) float f32x4_t;

__device__ __forceinline__ float sigmoidf_(float x) { return 1.f / (1.f + expf(-x)); }

// split 8 fp32 -> hi/lo bf16x8 fragments (validated round 4, absmax 0.0)
__device__ __forceinline__ void split8(const float* p, bf16x8_t& Ahi_, bf16x8_t& Alo_) {
    union { bf16x8_t v; unsigned u[4]; } hi, lo;
#pragma unroll
    for (int ii = 0; ii < 4; ++ii) {
        float pa = p[2 * ii], pb = p[2 * ii + 1];
        unsigned ua = __float_as_uint(pa), ub = __float_as_uint(pb);
        hi.u[ii] = (ua >> 16) | (ub & 0xFFFF0000u);
        float la = pa - __uint_as_float(ua & 0xFFFF0000u);
        float lb = pb - __uint_as_float(ub & 0xFFFF0000u);
        lo.u[ii] = (__float_as_uint(la) >> 16) | (__float_as_uint(lb) & 0xFFFF0000u);
    }
    Ahi_ = hi.v; Alo_ = lo.v;
}

// Fused fill: in_linear + Bfat pre-pack + Wg pre-pack (independent work).
__global__ __launch_bounds__(256) void k_fill(const float* __restrict__ x,
                                              const float* __restrict__ Win,
                                              const float* __restrict__ bin,
                                              const float* __restrict__ W2,
                                              const float* __restrict__ b2,
                                              const float* __restrict__ Wih,
                                              const float* __restrict__ Whh,
                                              float* __restrict__ out,
                                              unsigned short* __restrict__ Bfat,
                                              unsigned short* __restrict__ Wg) {
    int idx = blockIdx.x * 256 + threadIdx.x;
    if (idx < FILL_A) {
        int n = idx >> 6, j = idx & 63;
        const float* xr = x + n * 32;
        const float* w = Win + j * 32;
        float acc = bin[j];
#pragma unroll
        for (int k = 0; k < 32; ++k) acc += xr[k] * w[k];
        out[idx] = fmaxf(acc, 0.f);
        return;
    }
    idx -= FILL_A;
    if (idx < FILL_B) {
        int i  = idx & 7;
        int l  = (idx >> 3) & 63;
        int nq = (idx >> 9) & 3;
        int h  = (idx >> 11) & 1;
        int ks = idx >> 12;
        int kap = ks * 32 + (l >> 4) * 8 + i;
        int f = nq * 16 + (l & 15);
        float w;
        if (kap < 4096) {
            int q = kap >> 6, d = kap & 63;
            w = W2[(size_t)(d * 64 + f) * 64 + q];
        } else {
            int d = kap - 4096;
            w = b2[d * 64 + f];
        }
        unsigned u = __float_as_uint(w);
        unsigned short outv;
        if (h == 0) {
            outv = (unsigned short)(u >> 16);
        } else {
            float lo = w - __uint_as_float(u & 0xFFFF0000u);
            outv = (unsigned short)(__float_as_uint(lo) >> 16);
        }
        Bfat[idx] = outv;
        return;
    }
    idx -= FILL_B;
    if (idx < FILL_C) {
        int i  = idx & 7;
        int l  = (idx >> 3) & 63;
        int t  = (idx >> 9) & 15;
        int h  = (idx >> 13) & 1;
        int ks = idx >> 14;
        int k = ks * 32 + (l >> 4) * 8 + i;
        int u = t * 16 + (l & 15);
        int j = u & 63, part = u >> 6;   // 0:r, 1:z, 2:i_n, 3:h_n
        float w = 0.f;
        if (part == 0) w = (k < 64) ? Wih[(size_t)j * 64 + k]          : Whh[(size_t)j * 64 + (k - 64)];
        if (part == 1) w = (k < 64) ? Wih[(size_t)(64 + j) * 64 + k]   : Whh[(size_t)(64 + j) * 64 + (k - 64)];
        if (part == 2) w = (k < 64) ? Wih[(size_t)(128 + j) * 64 + k]  : 0.f;
        if (part == 3) w = (k < 64) ? 0.f : Whh[(size_t)(128 + j) * 64 + (k - 64)];
        unsigned uu = __float_as_uint(w);
        unsigned short outv;
        if (h == 0) {
            outv = (unsigned short)(uu >> 16);
        } else {
            float lo = w - __uint_as_float(uu & 0xFFFF0000u);
            outv = (unsigned short)(__float_as_uint(lo) >> 16);
        }
        Wg[idx] = outv;
    }
}

// edge MLP layer 1, writing rows in dst-sorted order (epos permutation).
__global__ __launch_bounds__(256) void k_edge_mlp1(const float* __restrict__ ea,
                                                   const float* __restrict__ W1,
                                                   const float* __restrict__ b1,
                                                   const int* __restrict__ epos,
                                                   float* __restrict__ eh) {
    int idx = blockIdx.x * 256 + threadIdx.x;
    if (idx >= Ee * 64) return;
    int e = idx >> 6, j = idx & 63;
    const float* ar = ea + e * 16;
    const float* w = W1 + j * 16;
    float acc = b1[j];
#pragma unroll
    for (int k = 0; k < 16; ++k) acc += ar[k] * w[k];
    eh[(size_t)epos[e] * 64 + j] = fmaxf(acc, 0.f);
}

// Fused counters: edge-degree histogram + batch histogram.
__global__ __launch_bounds__(256) void k_prep_count(const int* __restrict__ ei,
                                                    const int* __restrict__ batch,
                                                    int* __restrict__ deg,
                                                    int* __restrict__ bcount) {
    int idx = blockIdx.x * 256 + threadIdx.x;
    if (idx < Ee) {
        atomicAdd(&deg[ei[Ee + idx]], 1);
    } else if (idx < Ee + Nn) {
        atomicAdd(&bcount[batch[idx - Ee]], 1);
    }
}

// Fused scans: block 0 = node rowptr scan, block 1 = batch bstart scan.
__global__ __launch_bounds__(256) void k_prep_scan(const int* __restrict__ deg,
                                                   const int* __restrict__ bcount,
                                                   int* __restrict__ rowptr,
                                                   int* __restrict__ wptr,
                                                   int* __restrict__ bstart) {
    if (blockIdx.x == 0) {
        __shared__ int part[256];
        int t = threadIdx.x;
        const int PER = (Nn + 255) / 256;   // 40
        int b0 = t * PER;
        int s = 0;
        for (int i = 0; i < PER; ++i) {
            int idx = b0 + i;
            if (idx < Nn) s += deg[idx];
        }
        part[t] = s;
        __syncthreads();
        for (int o = 1; o < 256; o <<= 1) {
            int u = (t >= o) ? part[t - o] : 0;
            __syncthreads();
            part[t] += u;
            __syncthreads();
        }
        int run = part[t] - s;   // exclusive prefix
        for (int i = 0; i < PER; ++i) {
            int idx = b0 + i;
            if (idx < Nn) {
                rowptr[idx] = run;
                wptr[idx] = run;
                run += deg[idx];
            }
        }
        if (t == 255) rowptr[Nn] = run;
    } else if (threadIdx.x < 64) {
        int lane = threadIdx.x;
        const int PER = (Bb + 63) / 64;   // 7
        int base = lane * PER;
        int v[PER];
        int s = 0;
#pragma unroll
        for (int i = 0; i < PER; ++i) {
            int idx = base + i;
            int c = (idx < Bb) ? bcount[idx] : 0;
            v[i] = s;
            s += c;
        }
        int inc = s;
#pragma unroll
        for (int o = 1; o < 64; o <<= 1) {
            int t = __shfl_up(inc, o, 64);
            if (lane >= o) inc += t;
        }
        int excl = inc - s;
        int total = __shfl(inc, 63, 64);
#pragma unroll
        for (int i = 0; i < PER; ++i) {
            int idx = base + i;
            if (idx < Bb) bstart[idx] = excl + v[i];
        }
        if (lane == 63) bstart[Bb] = total;
    }
}

// Counting-sort scatter: srcs[] in dst-sorted order; epos[e] = sorted slot.
__global__ __launch_bounds__(256) void k_sort_edges(const int* __restrict__ ei,
                                                    int* __restrict__ wptr,
                                                    int* __restrict__ srcs,
                                                    int* __restrict__ epos) {
    int e = blockIdx.x * 256 + threadIdx.x;
    if (e >= Ee) return;
    int d = ei[Ee + e];
    int p = atomicAdd(&wptr[d], 1);
    srcs[p] = ei[e];
    epos[e] = p;
}

// Edge-direct message pass over SORTED edges, K-split across blockIdx.y,
// 128 edges/block, 256 threads, 2 M-tiles/wave (R13 wave shape). A pre-split
// hi/lo once in prologue; scaled ks: U = A.B zero-C chain then acc += q*U
// (q per output row via ehs_t broadcast float4 — R14-validated numerics);
// bias ks (>=128): MFMA directly into acc. Rolling distance-1 B prefetch.
__global__ __launch_bounds__(256) void k_msg_mfma(const float* __restrict__ out,
                                                  const float* __restrict__ eh,
                                                  const unsigned short* __restrict__ Bfat,
                                                  const int* __restrict__ srcs_g,
                                                  float* __restrict__ msgbuf,
                                                  int nsplit) {
    __shared__ float ehs_t[17][128];   // transposed q-window: [qi][edge]
    __shared__ int srcs[128];
    int tid = threadIdx.x;
    int ebase = blockIdx.x * 128;
    int ksplit = blockIdx.y;

    int ks0 = (KSTEPS * ksplit) / nsplit;
    int ks1 = (KSTEPS * (ksplit + 1)) / nsplit;
    int q0 = ks0 >> 1;
    int qn = ((min(ks1, 128) - 1) >> 1) - q0 + 1;           // <= 17

    {   // stage srcs + transposed ehs window: 2 threads per edge
        int el = tid >> 1, seg = tid & 1;
        int eg = ebase + el;
        bool v = eg < Ee;
        if (seg == 0) srcs[el] = v ? srcs_g[eg] : 0;
        const float* erow = eh + (size_t)eg * 64 + q0;
        for (int j = seg; j < qn; j += 2)
            ehs_t[j][el] = v ? erow[j] : 0.f;
    }
    __syncthreads();

    int lane = tid & 63;
    int wtile = tid >> 6;
    int m16 = lane & 15;
    int g = lane >> 4;
    int erA = wtile * 32 + m16;
    int erB = erA + 16;

    // A fragments pre-split hi/lo: tiles {A,B} x parity {even a0, odd a1}
    bf16x8_t A0h[2], A0l[2], A1h[2], A1l[2];
    {
        const float* rA = out + (size_t)srcs[erA] * 64;
        const float* rB = out + (size_t)srcs[erB] * 64;
        float a[8];
        float4 v0, v1;
        v0 = *(const float4*)(rA + g * 8);      v1 = *(const float4*)(rA + g * 8 + 4);
        a[0]=v0.x; a[1]=v0.y; a[2]=v0.z; a[3]=v0.w; a[4]=v1.x; a[5]=v1.y; a[6]=v1.z; a[7]=v1.w;
        split8(a, A0h[0], A0l[0]);
        v0 = *(const float4*)(rA + 32 + g * 8); v1 = *(const float4*)(rA + 36 + g * 8);
        a[0]=v0.x; a[1]=v0.y; a[2]=v0.z; a[3]=v0.w; a[4]=v1.x; a[5]=v1.y; a[6]=v1.z; a[7]=v1.w;
        split8(a, A1h[0], A1l[0]);
        v0 = *(const float4*)(rB + g * 8);      v1 = *(const float4*)(rB + g * 8 + 4);
        a[0]=v0.x; a[1]=v0.y; a[2]=v0.z; a[3]=v0.w; a[4]=v1.x; a[5]=v1.y; a[6]=v1.z; a[7]=v1.w;
        split8(a, A0h[1], A0l[1]);
        v0 = *(const float4*)(rB + 32 + g * 8); v1 = *(const float4*)(rB + 36 + g * 8);
        a[0]=v0.x; a[1]=v0.y; a[2]=v0.z; a[3]=v0.w; a[4]=v1.x; a[5]=v1.y; a[6]=v1.z; a[7]=v1.w;
        split8(a, A1h[1], A1l[1]);
    }

    f32x4_t acc[2][4];   // [tile][nq]
#pragma unroll
    for (int t = 0; t < 2; ++t)
#pragma unroll
        for (int nq = 0; nq < 4; ++nq) acc[t][nq] = (f32x4_t){0.f, 0.f, 0.f, 0.f};

    auto loadB = [&](int ks, bf16x8_t (&bh)[4], bf16x8_t (&bl)[4]) {
        const unsigned short* bstep = Bfat + (size_t)ks * 4096;
#pragma unroll
        for (int nq = 0; nq < 4; ++nq) {
            bh[nq] = *(const bf16x8_t*)(bstep + ((size_t)(nq * 64 + lane)) * 8);
            bl[nq] = *(const bf16x8_t*)(bstep + ((size_t)((4 + nq) * 64 + lane)) * 8);
        }
    };
    // scaled ks: U = Al.bh + Ah.bl + Ah.bh (zero-C chain); acc += q_row * U
    auto computeP = [&](int kp, const bf16x8_t (&Ah)[2], const bf16x8_t (&Al)[2],
                        const bf16x8_t (&bh)[4], const bf16x8_t (&bl)[4]) {
        int qi = (kp >> 1) - q0;
        if (qi < 0) qi = 0;   // guarded: only pre-ks0 even steps, never computed
#pragma unroll
        for (int t = 0; t < 2; ++t) {
            float4 q4 = *(const float4*)&ehs_t[qi][wtile * 32 + t * 16 + g * 4];
#pragma unroll
            for (int nq = 0; nq < 4; ++nq) {
                f32x4_t U = (f32x4_t){0.f, 0.f, 0.f, 0.f};
                U = __builtin_amdgcn_mfma_f32_16x16x32_bf16(Al[t], bh[nq], U, 0, 0, 0);
                U = __builtin_amdgcn_mfma_f32_16x16x32_bf16(Ah[t], bl[nq], U, 0, 0, 0);
                U = __builtin_amdgcn_mfma_f32_16x16x32_bf16(Ah[t], bh[nq], U, 0, 0, 0);
                acc[t][nq][0] += q4.x * U[0];
                acc[t][nq][1] += q4.y * U[1];
                acc[t][nq][2] += q4.z * U[2];
                acc[t][nq][3] += q4.w * U[3];
            }
        }
    };
    // bias ks (>=128): accumulate directly (q == 1)
    auto computeB = [&](const bf16x8_t (&Ah)[2], const bf16x8_t (&Al)[2],
                        const bf16x8_t (&bh)[4], const bf16x8_t (&bl)[4]) {
#pragma unroll
        for (int t = 0; t < 2; ++t)
#pragma unroll
            for (int nq = 0; nq < 4; ++nq) {
                acc[t][nq] = __builtin_amdgcn_mfma_f32_16x16x32_bf16(Al[t], bh[nq], acc[t][nq], 0, 0, 0);
                acc[t][nq] = __builtin_amdgcn_mfma_f32_16x16x32_bf16(Ah[t], bl[nq], acc[t][nq], 0, 0, 0);
                acc[t][nq] = __builtin_amdgcn_mfma_f32_16x16x32_bf16(Ah[t], bh[nq], acc[t][nq], 0, 0, 0);
            }
    };

    // distance-1 software pipeline over parity-unrolled ks loop:
    //   bO(kp+1) issued before even compute; bE(kp+2) issued before odd.
    bf16x8_t bEh[4], bEl[4], bOh[4], bOl[4];
    int kp0 = ks0 & ~1;
    loadB(kp0, bEh, bEl);
    for (int kp = kp0; kp < ks1; kp += 2) {
        bool hasOdd = (kp + 1 < ks1);
        if (hasOdd) loadB(kp + 1, bOh, bOl);
        if (kp >= ks0) {
            if (kp < 128) computeP(kp, A0h, A0l, bEh, bEl);
            else          computeB(A0h, A0l, bEh, bEl);
        }
        if (kp + 2 < ks1) loadB(kp + 2, bEh, bEl);
        if (hasOdd) {
            if (kp + 1 < 128) computeP(kp + 1, A1h, A1l, bOh, bOl);
            else              computeB(A1h, A1l, bOh, bOl);
        }
    }

    // epilogue: plain stores (64B-granular across the 16 lanes of each g-group)
#pragma unroll
    for (int t = 0; t < 2; ++t) {
#pragma unroll
        for (int r = 0; r < 4; ++r) {
            int el = wtile * 32 + t * 16 + g * 4 + r;
            int eg = ebase + el;
            if (eg >= Ee) continue;
            float* mrow = msgbuf + ((size_t)ksplit * Ee + eg) * 64 + m16;
#pragma unroll
            for (int nq = 0; nq < 4; ++nq)
                mrow[nq * 16] = acc[t][nq][r];
        }
    }
}

// Fused GRU: stage m = relu(segsum(msgbuf)/deg + b_conv) and h = out in LDS;
// gates via split-bf16 MFMA (A=[m|h] K=128, N=256); combine in epilogue.
__global__ __launch_bounds__(256) void k_gru_mfma(const float* __restrict__ msgbuf,
                                                  const int* __restrict__ rowptr,
                                                  const float* __restrict__ bconv,
                                                  const unsigned short* __restrict__ Wg,
                                                  const float* __restrict__ bih,
                                                  const float* __restrict__ bhh,
                                                  float* __restrict__ out,
                                                  int nsplit) {
    __shared__ float ms[64][68];
    __shared__ float hs[64][68];
    int tid = threadIdx.x;
    int nbase = blockIdx.x * 64;

    {   // stage: 4 threads per node, 16 cols each; segment-sum msgbuf range
        int nl = tid >> 2, seg = tid & 3;
        int ng = nbase + nl;
        bool v = ng < Nn;
        int p0 = v ? rowptr[ng] : 0;
        int p1 = v ? rowptr[ng + 1] : 0;
        int dg = p1 - p0;
        float rc = 1.f / (float)(dg < 1 ? 1 : dg);
        float s[16];
#pragma unroll
        for (int i = 0; i < 16; ++i) s[i] = 0.f;
        for (int sp = 0; sp < nsplit; ++sp) {
            const float* mb = msgbuf + (size_t)sp * Ee * 64;
            for (int p = p0; p < p1; ++p) {
                const float* mrow = mb + (size_t)p * 64 + seg * 16;
#pragma unroll
                for (int c4 = 0; c4 < 4; ++c4) {
                    float4 t4 = *(const float4*)(mrow + c4 * 4);
                    s[c4 * 4 + 0] += t4.x;
                    s[c4 * 4 + 1] += t4.y;
                    s[c4 * 4 + 2] += t4.z;
                    s[c4 * 4 + 3] += t4.w;
                }
            }
        }
        const float* hrow = out + (size_t)ng * 64 + seg * 16;
        float4 z = make_float4(0.f, 0.f, 0.f, 0.f);
#pragma unroll
        for (int c4 = 0; c4 < 4; ++c4) {
            int col = seg * 16 + c4 * 4;
            float4 hv = v ? *(const float4*)(hrow + c4 * 4) : z;
            ms[nl][col + 0] = fmaxf(s[c4 * 4 + 0] * rc + bconv[col + 0], 0.f);
            ms[nl][col + 1] = fmaxf(s[c4 * 4 + 1] * rc + bconv[col + 1], 0.f);
            ms[nl][col + 2] = fmaxf(s[c4 * 4 + 2] * rc + bconv[col + 2], 0.f);
            ms[nl][col + 3] = fmaxf(s[c4 * 4 + 3] * rc + bconv[col + 3], 0.f);
            *(float4*)&hs[nl][col] = hv;
        }
    }
    __syncthreads();

    int lane = tid & 63;
    int wtile = tid >> 6;
    int m16 = lane & 15;
    int g = lane >> 4;
    int er = wtile * 16 + m16;

    f32x4_t acc[16];
#pragma unroll
    for (int t = 0; t < 16; ++t) acc[t] = (f32x4_t){0.f, 0.f, 0.f, 0.f};

#pragma unroll
    for (int ks = 0; ks < 4; ++ks) {
        const float* src = (ks < 2) ? &ms[er][ks * 32 + g * 8]
                                    : &hs[er][(ks - 2) * 32 + g * 8];
        float p[8];
#pragma unroll
        for (int ii = 0; ii < 8; ++ii) p[ii] = src[ii];
        bf16x8_t Ahi, Alo;
        split8(p, Ahi, Alo);
        const unsigned short* bstep = Wg + (size_t)ks * (2 * 16 * 512);
#pragma unroll
        for (int t = 0; t < 16; ++t) {
            bf16x8_t bhi = *(const bf16x8_t*)(bstep + ((size_t)t * 64 + lane) * 8);
            bf16x8_t blo = *(const bf16x8_t*)(bstep + ((size_t)(16 + t) * 64 + lane) * 8);
            acc[t] = __builtin_amdgcn_mfma_f32_16x16x32_bf16(Ahi, bhi, acc[t], 0, 0, 0);
            acc[t] = __builtin_amdgcn_mfma_f32_16x16x32_bf16(Ahi, blo, acc[t], 0, 0, 0);
            acc[t] = __builtin_amdgcn_mfma_f32_16x16x32_bf16(Alo, bhi, acc[t], 0, 0, 0);
        }
    }

    // epilogue: GRU combine, fully lane-local
#pragma unroll
    for (int t2 = 0; t2 < 4; ++t2) {
        int jj = t2 * 16 + m16;
        float br = bih[jj] + bhh[jj];
        float bz = bih[64 + jj] + bhh[64 + jj];
        float bin_ = bih[128 + jj];
        float bhn = bhh[128 + jj];
#pragma unroll
        for (int r = 0; r < 4; ++r) {
            int nl2 = wtile * 16 + g * 4 + r;
            int ng2 = nbase + nl2;
            if (ng2 >= Nn) continue;
            float rg = sigmoidf_(acc[t2][r] + br);
            float z  = sigmoidf_(acc[4 + t2][r] + bz);
            float nn = tanhf(acc[8 + t2][r] + bin_ + rg * (acc[12 + t2][r] + bhn));
            float hv = hs[nl2][jj];
            out[(size_t)ng2 * 64 + jj] = (1.f - z) * nn + z * hv;
        }
    }
}

// Block-wide reductions (uniform result broadcast to all 256 threads).
__device__ __forceinline__ float block_reduce_max_(float v, float* red, int tid) {
#pragma unroll
    for (int o = 32; o; o >>= 1) v = fmaxf(v, __shfl_xor(v, o, 64));
    if ((tid & 63) == 0) red[tid >> 6] = v;
    __syncthreads();
    float r = fmaxf(fmaxf(red[0], red[1]), fmaxf(red[2], red[3]));
    __syncthreads();
    return r;
}
__device__ __forceinline__ float block_reduce_sum_(float v, float* red, int tid) {
#pragma unroll
    for (int o = 32; o; o >>= 1) v += __shfl_xor(v, o, 64);
    if ((tid & 63) == 0) red[tid >> 6] = v;
    __syncthreads();
    float r = (red[0] + red[1]) + (red[2] + red[3]);
    __syncthreads();
    return r;
}

// Fused Set2Set: one 256-thread block per graph (round 6, validated).
__global__ __launch_bounds__(256) void k_set2set(const float* __restrict__ out,
                                                 const int* __restrict__ bstart,
                                                 const float* __restrict__ Wil,
                                                 const float* __restrict__ bil,
                                                 const float* __restrict__ Whl,
                                                 const float* __restrict__ bhl,
                                                 const float* __restrict__ Wo1,
                                                 const float* __restrict__ bo1,
                                                 const float* __restrict__ Wo2,
                                                 const float* __restrict__ bo2,
                                                 float* __restrict__ outp) {
    __shared__ float qs[128];        // q_star = [q | r]
    __shared__ float hs2[64];        // hl
    __shared__ float cs[64];         // cl
    __shared__ float g_lds[256];     // LSTM gates
    __shared__ float e_lds[S2S_CHUNK];
    __shared__ float red[4];
    __shared__ float rpart[4][64];

    int b = blockIdx.x, tid = threadIdx.x;
    int lane = tid & 63, wv = tid >> 6;
    int s = bstart[b], eend = bstart[b + 1];
    int cntb = eend - s;

    if (tid < 128) qs[tid] = 0.f;
    if (tid < 64) { hs2[tid] = 0.f; cs[tid] = 0.f; }
    __syncthreads();

    for (int step = 0; step < 3; ++step) {
        {
            int u = tid;
            float acc = bil[u] + bhl[u];
            const float4* wi = (const float4*)(Wil + (size_t)u * 128);
#pragma unroll
            for (int k4 = 0; k4 < 32; ++k4) {
                float4 w = wi[k4];
                acc += qs[k4 * 4 + 0] * w.x + qs[k4 * 4 + 1] * w.y +
                       qs[k4 * 4 + 2] * w.z + qs[k4 * 4 + 3] * w.w;
            }
            const float4* wh = (const float4*)(Whl + (size_t)u * 64);
#pragma unroll
            for (int k4 = 0; k4 < 16; ++k4) {
                float4 w = wh[k4];
                acc += hs2[k4 * 4 + 0] * w.x + hs2[k4 * 4 + 1] * w.y +
                       hs2[k4 * 4 + 2] * w.z + hs2[k4 * 4 + 3] * w.w;
            }
            g_lds[u] = acc;
        }
        __syncthreads();
        if (tid < 64) {   // torch order i,f,g,o
            float c = sigmoidf_(g_lds[64 + tid]) * cs[tid] +
                      sigmoidf_(g_lds[tid]) * tanhf(g_lds[128 + tid]);
            cs[tid] = c;
            float h = sigmoidf_(g_lds[192 + tid]) * tanhf(c);
            hs2[tid] = h;
            qs[tid] = h;   // q = hl
        }
        __syncthreads();

        // attention: chunked two-pass softmax, node-parallel
        float gmax = -INFINITY, gsum = 0.f, racc = 0.f;
        for (int c0 = s; c0 < eend; c0 += S2S_CHUNK) {
            int clen = min(S2S_CHUNK, eend - c0);
            for (int i = tid; i < clen; i += 256) {
                const float4* orow = (const float4*)(out + (size_t)(c0 + i) * 64);
                float a0 = 0.f, a1 = 0.f, a2 = 0.f, a3 = 0.f;
#pragma unroll
                for (int k4 = 0; k4 < 16; k4 += 4) {
                    float4 o0 = orow[k4], o1 = orow[k4 + 1], o2 = orow[k4 + 2], o3 = orow[k4 + 3];
                    a0 += o0.x * qs[k4 * 4 + 0]  + o0.y * qs[k4 * 4 + 1]  + o0.z * qs[k4 * 4 + 2]  + o0.w * qs[k4 * 4 + 3];
                    a1 += o1.x * qs[k4 * 4 + 4]  + o1.y * qs[k4 * 4 + 5]  + o1.z * qs[k4 * 4 + 6]  + o1.w * qs[k4 * 4 + 7];
                    a2 += o2.x * qs[k4 * 4 + 8]  + o2.y * qs[k4 * 4 + 9]  + o2.z * qs[k4 * 4 + 10] + o2.w * qs[k4 * 4 + 11];
                    a3 += o3.x * qs[k4 * 4 + 12] + o3.y * qs[k4 * 4 + 13] + o3.z * qs[k4 * 4 + 14] + o3.w * qs[k4 * 4 + 15];
                }
                e_lds[i] = (a0 + a1) + (a2 + a3);
            }
            __syncthreads();
            float m = -INFINITY;
            for (int i = tid; i < clen; i += 256) m = fmaxf(m, e_lds[i]);
            float cmax = block_reduce_max_(m, red, tid);
            float nm = fmaxf(gmax, cmax);
            float scale = expf(gmax - nm);   // 0 on first chunk (gmax=-inf)
            gsum *= scale; racc *= scale;
            float lsum = 0.f;
            for (int i = tid; i < clen; i += 256) {
                float av = expf(e_lds[i] - nm);
                e_lds[i] = av;
                lsum += av;
            }
            gsum += block_reduce_sum_(lsum, red, tid);
            for (int i = wv; i < clen; i += 4)
                racc += e_lds[i] * out[(size_t)(c0 + i) * 64 + lane];
            gmax = nm;
            __syncthreads();
        }
        rpart[wv][lane] = racc;
        __syncthreads();
        if (tid < 64) {
            float r = (rpart[0][tid] + rpart[1][tid]) + (rpart[2][tid] + rpart[3][tid]);
            qs[64 + tid] = (cntb > 0) ? r / gsum : 0.f;
        }
        __syncthreads();
    }

    // final MLP (wave 0)
    if (tid < 64) {
        float acc = bo1[tid];
        const float4* w = (const float4*)(Wo1 + (size_t)tid * 128);
#pragma unroll
        for (int k4 = 0; k4 < 32; ++k4) {
            float4 wv4 = w[k4];
            acc += qs[k4 * 4 + 0] * wv4.x + qs[k4 * 4 + 1] * wv4.y +
                   qs[k4 * 4 + 2] * wv4.z + qs[k4 * 4 + 3] * wv4.w;
        }
        acc = fmaxf(acc, 0.f);
        float t = acc * Wo2[tid];
#pragma unroll
        for (int o = 32; o; o >>= 1) t += __shfl_xor(t, o, 64);
        if (tid == 0) outp[b] = t + bo2[0];
    }
}

extern "C" void kernel_launch(void* const* d_in, const int* in_sizes, int n_in,
                              void* d_out, int out_size, void* d_ws, size_t ws_size,
                              hipStream_t stream) {
    const float* x        = (const float*)d_in[0];
    const float* ea       = (const float*)d_in[1];
    const float* W_in     = (const float*)d_in[2];
    const float* b_in     = (const float*)d_in[3];
    const float* W_e1     = (const float*)d_in[4];
    const float* b_e1     = (const float*)d_in[5];
    const float* W_e2     = (const float*)d_in[6];
    const float* b_e2     = (const float*)d_in[7];
    const float* b_conv   = (const float*)d_in[8];
    const float* W_ih     = (const float*)d_in[9];
    const float* b_ih     = (const float*)d_in[10];
    const float* W_hh     = (const float*)d_in[11];
    const float* b_hh     = (const float*)d_in[12];
    const float* W_ih_l   = (const float*)d_in[13];
    const float* b_ih_l   = (const float*)d_in[14];
    const float* W_hh_l   = (const float*)d_in[15];
    const float* b_hh_l   = (const float*)d_in[16];
    const float* W_o1     = (const float*)d_in[17];
    const float* b_o1     = (const float*)d_in[18];
    const float* W_o2     = (const float*)d_in[19];
    const float* b_o2     = (const float*)d_in[20];
    const int*   ei       = (const int*)d_in[21];
    const int*   batch    = (const int*)d_in[22];
    float* outp = (float*)d_out;

    char* base = (char*)d_ws;
    size_t off = 0;
    auto carve = [&](size_t bytes) -> void* {
        void* p = base + off;
        off = (off + bytes + 255) & ~(size_t)255;
        return p;
    };

    // nsplit = 4
    int ns = 4;
    float *out, *msgbuf, *eh;
    unsigned short *Bfat, *Wg;
    int *srcs, *epos, *rowptr, *wptr, *deg, *bcount, *bstart;
    for (;; ns >>= 1) {
        off = 0;
        out    = (float*)carve((size_t)Nn * 64 * 4);
        msgbuf = (float*)carve((size_t)ns * Ee * 64 * 4);
        eh     = (float*)carve((size_t)Ee * 64 * 4);
        Bfat   = (unsigned short*)carve((size_t)KSTEPS * 4096 * 2);
        Wg     = (unsigned short*)carve((size_t)4 * 2 * 16 * 64 * 8 * 2);
        srcs   = (int*)carve((size_t)Ee * 4);
        epos   = (int*)carve((size_t)Ee * 4);
        rowptr = (int*)carve((size_t)(Nn + 1) * 4);
        wptr   = (int*)carve((size_t)Nn * 4);
        deg    = (int*)carve((size_t)Nn * 4);
        bcount = (int*)carve((size_t)Bb * 4);
        bstart = (int*)carve((size_t)(Bb + 1) * 4);
        if (off <= ws_size || ns == 1) break;
    }
    if (off > ws_size) return;

    hipMemsetAsync(deg, 0, (size_t)Nn * 4, stream);
    hipMemsetAsync(bcount, 0, (size_t)Bb * 4, stream);

    k_prep_count<<<(Ee + Nn + 255) / 256, 256, 0, stream>>>(ei, batch, deg, bcount);
    k_prep_scan<<<2, 256, 0, stream>>>(deg, bcount, rowptr, wptr, bstart);
    k_sort_edges<<<(Ee + 255) / 256, 256, 0, stream>>>(ei, wptr, srcs, epos);

    k_fill<<<(FILL_A + FILL_B + FILL_C + 255) / 256, 256, 0, stream>>>(
        x, W_in, b_in, W_e2, b_e2, W_ih, W_hh, out, Bfat, Wg);
    k_edge_mlp1<<<(Ee * 64) / 256, 256, 0, stream>>>(ea, W_e1, b_e1, epos, eh);

    int eblocks = (Ee + 127) / 128;   // 157
    int nblocks = (Nn + 63) / 64;     // 157
    for (int it = 0; it < 3; ++it) {
        k_msg_mfma<<<dim3(eblocks, ns), 256, 0, stream>>>(out, eh, Bfat, srcs, msgbuf, ns);
        k_gru_mfma<<<nblocks, 256, 0, stream>>>(msgbuf, rowptr, b_conv, Wg, b_ih, b_hh, out, ns);
    }

    k_set2set<<<Bb, 256, 0, stream>>>(out, bstart, W_ih_l, b_ih_l, W_hh_l, b_hh_l,
                                      W_o1, b_o1, W_o2, b_o2, outp);
}

// Round 12
// 330.665 us; speedup vs baseline: 1.1495x; 1.1495x over previous
//
#include <hip/hip_runtime.h>
#include <math.h>

// MPNN forward. Round 17 (final polish):
//  - REVERT R16 post-scale k_msg (61.6us: zero-C U-chain created a per-ks
//    MFMA->VALU cross-pipe dependency; VALUBusy UP 28->32, MfmaUtil DOWN).
//    k_msg restored to R13 exactly (45.6us, best of 7 structures probed:
//    LDS-B 54.8 / reg-A 54.2 / sorted 45.6 / ns8 47 / 4-tile 71 / postscale
//    61.6). Floor robust to occupancy x2.4, prefetch, atomics, VALU mix =>
//    stream-overlap structural stall; stop touching k_msg.
//  - Launch cut: k_prep_count's two histograms folded into k_fill as an
//    extra index range (independent work, ordering vs memsets unchanged).
//    13 -> 12 launches.
//  - R13: rolling B prefetch, prep_scan/fill fusion. R11: dst-sorted edges,
//    plain-store msgbuf (no atomics). R10: reg-A, direct-L2 B, no barriers.
//  - Rounds 1-9: K-split edge MFMA, fused GRU MFMA, split-bf16 hi/lo MFMA,
//    Bfat/Wg pre-pack, 256-thr set2set, parallel scans.

#define Nn 10000
#define Ee 20000
#define Bb 400
#define KSTEPS 130   // 128 (q,d) steps + 2 bias steps (K = 4160)
#define S2S_CHUNK 1024

#define FILL_A (Nn * 64)              // in_linear outputs
#define FILL_B (KSTEPS * 4096)        // Bfat elements
#define FILL_C (4 * 2 * 16 * 64 * 8)  // Wg elements
#define FILL_D (Ee + Nn)              // deg + bcount histograms

typedef __attribute__((ext_vector_type(8))) short bf16x8_t;
typedef __attribute__((ext_vector_type(4))) float f32x4_t;

__device__ __forceinline__ float sigmoidf_(float x) { return 1.f / (1.f + expf(-x)); }

// split 8 fp32 -> hi/lo bf16x8 fragments (validated round 4, absmax 0.0)
__device__ __forceinline__ void split8(const float* p, bf16x8_t& Ahi_, bf16x8_t& Alo_) {
    union { bf16x8_t v; unsigned u[4]; } hi, lo;
#pragma unroll
    for (int ii = 0; ii < 4; ++ii) {
        float pa = p[2 * ii], pb = p[2 * ii + 1];
        unsigned ua = __float_as_uint(pa), ub = __float_as_uint(pb);
        hi.u[ii] = (ua >> 16) | (ub & 0xFFFF0000u);
        float la = pa - __uint_as_float(ua & 0xFFFF0000u);
        float lb = pb - __uint_as_float(ub & 0xFFFF0000u);
        lo.u[ii] = (__float_as_uint(la) >> 16) | (__float_as_uint(lb) & 0xFFFF0000u);
    }
    Ahi_ = hi.v; Alo_ = lo.v;
}

// Fused fill: in_linear + Bfat pre-pack + Wg pre-pack + deg/batch histograms.
__global__ __launch_bounds__(256) void k_fill(const float* __restrict__ x,
                                              const float* __restrict__ Win,
                                              const float* __restrict__ bin,
                                              const float* __restrict__ W2,
                                              const float* __restrict__ b2,
                                              const float* __restrict__ Wih,
                                              const float* __restrict__ Whh,
                                              const int* __restrict__ ei,
                                              const int* __restrict__ batch,
                                              float* __restrict__ out,
                                              unsigned short* __restrict__ Bfat,
                                              unsigned short* __restrict__ Wg,
                                              int* __restrict__ deg,
                                              int* __restrict__ bcount) {
    int idx = blockIdx.x * 256 + threadIdx.x;
    if (idx < FILL_A) {
        int n = idx >> 6, j = idx & 63;
        const float* xr = x + n * 32;
        const float* w = Win + j * 32;
        float acc = bin[j];
#pragma unroll
        for (int k = 0; k < 32; ++k) acc += xr[k] * w[k];
        out[idx] = fmaxf(acc, 0.f);
        return;
    }
    idx -= FILL_A;
    if (idx < FILL_B) {
        int i  = idx & 7;
        int l  = (idx >> 3) & 63;
        int nq = (idx >> 9) & 3;
        int h  = (idx >> 11) & 1;
        int ks = idx >> 12;
        int kap = ks * 32 + (l >> 4) * 8 + i;
        int f = nq * 16 + (l & 15);
        float w;
        if (kap < 4096) {
            int q = kap >> 6, d = kap & 63;
            w = W2[(size_t)(d * 64 + f) * 64 + q];
        } else {
            int d = kap - 4096;
            w = b2[d * 64 + f];
        }
        unsigned u = __float_as_uint(w);
        unsigned short outv;
        if (h == 0) {
            outv = (unsigned short)(u >> 16);
        } else {
            float lo = w - __uint_as_float(u & 0xFFFF0000u);
            outv = (unsigned short)(__float_as_uint(lo) >> 16);
        }
        Bfat[idx] = outv;
        return;
    }
    idx -= FILL_B;
    if (idx < FILL_C) {
        int i  = idx & 7;
        int l  = (idx >> 3) & 63;
        int t  = (idx >> 9) & 15;
        int h  = (idx >> 13) & 1;
        int ks = idx >> 14;
        int k = ks * 32 + (l >> 4) * 8 + i;
        int u = t * 16 + (l & 15);
        int j = u & 63, part = u >> 6;   // 0:r, 1:z, 2:i_n, 3:h_n
        float w = 0.f;
        if (part == 0) w = (k < 64) ? Wih[(size_t)j * 64 + k]          : Whh[(size_t)j * 64 + (k - 64)];
        if (part == 1) w = (k < 64) ? Wih[(size_t)(64 + j) * 64 + k]   : Whh[(size_t)(64 + j) * 64 + (k - 64)];
        if (part == 2) w = (k < 64) ? Wih[(size_t)(128 + j) * 64 + k]  : 0.f;
        if (part == 3) w = (k < 64) ? 0.f : Whh[(size_t)(128 + j) * 64 + (k - 64)];
        unsigned uu = __float_as_uint(w);
        unsigned short outv;
        if (h == 0) {
            outv = (unsigned short)(uu >> 16);
        } else {
            float lo = w - __uint_as_float(uu & 0xFFFF0000u);
            outv = (unsigned short)(__float_as_uint(lo) >> 16);
        }
        Wg[idx] = outv;
        return;
    }
    idx -= FILL_C;
    if (idx < FILL_D) {
        if (idx < Ee) atomicAdd(&deg[ei[Ee + idx]], 1);
        else          atomicAdd(&bcount[batch[idx - Ee]], 1);
    }
}

// edge MLP layer 1, writing rows in dst-sorted order (epos permutation).
__global__ __launch_bounds__(256) void k_edge_mlp1(const float* __restrict__ ea,
                                                   const float* __restrict__ W1,
                                                   const float* __restrict__ b1,
                                                   const int* __restrict__ epos,
                                                   float* __restrict__ eh) {
    int idx = blockIdx.x * 256 + threadIdx.x;
    if (idx >= Ee * 64) return;
    int e = idx >> 6, j = idx & 63;
    const float* ar = ea + e * 16;
    const float* w = W1 + j * 16;
    float acc = b1[j];
#pragma unroll
    for (int k = 0; k < 16; ++k) acc += ar[k] * w[k];
    eh[(size_t)epos[e] * 64 + j] = fmaxf(acc, 0.f);
}

// Fused scans: block 0 = node rowptr scan, block 1 = batch bstart scan.
__global__ __launch_bounds__(256) void k_prep_scan(const int* __restrict__ deg,
                                                   const int* __restrict__ bcount,
                                                   int* __restrict__ rowptr,
                                                   int* __restrict__ wptr,
                                                   int* __restrict__ bstart) {
    if (blockIdx.x == 0) {
        __shared__ int part[256];
        int t = threadIdx.x;
        const int PER = (Nn + 255) / 256;   // 40
        int b0 = t * PER;
        int s = 0;
        for (int i = 0; i < PER; ++i) {
            int idx = b0 + i;
            if (idx < Nn) s += deg[idx];
        }
        part[t] = s;
        __syncthreads();
        for (int o = 1; o < 256; o <<= 1) {
            int u = (t >= o) ? part[t - o] : 0;
            __syncthreads();
            part[t] += u;
            __syncthreads();
        }
        int run = part[t] - s;   // exclusive prefix
        for (int i = 0; i < PER; ++i) {
            int idx = b0 + i;
            if (idx < Nn) {
                rowptr[idx] = run;
                wptr[idx] = run;
                run += deg[idx];
            }
        }
        if (t == 255) rowptr[Nn] = run;
    } else if (threadIdx.x < 64) {
        int lane = threadIdx.x;
        const int PER = (Bb + 63) / 64;   // 7
        int base = lane * PER;
        int v[PER];
        int s = 0;
#pragma unroll
        for (int i = 0; i < PER; ++i) {
            int idx = base + i;
            int c = (idx < Bb) ? bcount[idx] : 0;
            v[i] = s;
            s += c;
        }
        int inc = s;
#pragma unroll
        for (int o = 1; o < 64; o <<= 1) {
            int t = __shfl_up(inc, o, 64);
            if (lane >= o) inc += t;
        }
        int excl = inc - s;
        int total = __shfl(inc, 63, 64);
#pragma unroll
        for (int i = 0; i < PER; ++i) {
            int idx = base + i;
            if (idx < Bb) bstart[idx] = excl + v[i];
        }
        if (lane == 63) bstart[Bb] = total;
    }
}

// Counting-sort scatter: srcs[] in dst-sorted order; epos[e] = sorted slot.
__global__ __launch_bounds__(256) void k_sort_edges(const int* __restrict__ ei,
                                                    int* __restrict__ wptr,
                                                    int* __restrict__ srcs,
                                                    int* __restrict__ epos) {
    int e = blockIdx.x * 256 + threadIdx.x;
    if (e >= Ee) return;
    int d = ei[Ee + e];
    int p = atomicAdd(&wptr[d], 1);
    srcs[p] = ei[e];
    epos[e] = p;
}

// Edge-direct message pass over SORTED edges, K-split across blockIdx.y,
// 128 edges/block, 256 threads (R13 verbatim). A in registers, B via rolling
// register prefetch (even/odd named buffers). Plain-store msgbuf epilogue.
__global__ __launch_bounds__(256) void k_msg_mfma(const float* __restrict__ out,
                                                  const float* __restrict__ eh,
                                                  const unsigned short* __restrict__ Bfat,
                                                  const int* __restrict__ srcs_g,
                                                  float* __restrict__ msgbuf,
                                                  int nsplit) {
    __shared__ float ehs[128][20];   // compact q-window [q0, q0+qn)
    __shared__ int srcs[128];
    int tid = threadIdx.x;
    int ebase = blockIdx.x * 128;
    int ksplit = blockIdx.y;

    int ks0 = (KSTEPS * ksplit) / nsplit;
    int ks1 = (KSTEPS * (ksplit + 1)) / nsplit;
    int q0 = ks0 >> 1;
    int qn = ((min(ks1, 128) - 1) >> 1) - q0 + 1;           // <= 17

    {   // stage srcs + ehs window: 2 threads per edge (edges already sorted)
        int el = tid >> 1, seg = tid & 1;
        int eg = ebase + el;
        bool v = eg < Ee;
        if (seg == 0) srcs[el] = v ? srcs_g[eg] : 0;
        const float* erow = eh + (size_t)eg * 64;
        for (int j = seg; j < qn; j += 2)
            ehs[el][j] = v ? erow[q0 + j] : 0.f;
    }
    __syncthreads();

    int lane = tid & 63;
    int wtile = tid >> 6;
    int m16 = lane & 15;
    int g = lane >> 4;
    int erA = wtile * 32 + m16;
    int erB = erA + 16;

    // A registers: per tile, half0 = cols [g*8, g*8+8), half1 = [32+g*8, ...)
    float a0[2][8], a1[2][8];
    {
        const float* rA = out + (size_t)srcs[erA] * 64;
        const float* rB = out + (size_t)srcs[erB] * 64;
        float4 v0, v1;
        v0 = *(const float4*)(rA + g * 8);      v1 = *(const float4*)(rA + g * 8 + 4);
        a0[0][0]=v0.x; a0[0][1]=v0.y; a0[0][2]=v0.z; a0[0][3]=v0.w;
        a0[0][4]=v1.x; a0[0][5]=v1.y; a0[0][6]=v1.z; a0[0][7]=v1.w;
        v0 = *(const float4*)(rA + 32 + g * 8); v1 = *(const float4*)(rA + 36 + g * 8);
        a1[0][0]=v0.x; a1[0][1]=v0.y; a1[0][2]=v0.z; a1[0][3]=v0.w;
        a1[0][4]=v1.x; a1[0][5]=v1.y; a1[0][6]=v1.z; a1[0][7]=v1.w;
        v0 = *(const float4*)(rB + g * 8);      v1 = *(const float4*)(rB + g * 8 + 4);
        a0[1][0]=v0.x; a0[1][1]=v0.y; a0[1][2]=v0.z; a0[1][3]=v0.w;
        a0[1][4]=v1.x; a0[1][5]=v1.y; a0[1][6]=v1.z; a0[1][7]=v1.w;
        v0 = *(const float4*)(rB + 32 + g * 8); v1 = *(const float4*)(rB + 36 + g * 8);
        a1[1][0]=v0.x; a1[1][1]=v0.y; a1[1][2]=v0.z; a1[1][3]=v0.w;
        a1[1][4]=v1.x; a1[1][5]=v1.y; a1[1][6]=v1.z; a1[1][7]=v1.w;
    }

    f32x4_t acc[2][4];
#pragma unroll
    for (int t = 0; t < 2; ++t)
#pragma unroll
        for (int nq = 0; nq < 4; ++nq) acc[t][nq] = (f32x4_t){0.f, 0.f, 0.f, 0.f};

    auto loadB = [&](int ks, bf16x8_t (&bh)[4], bf16x8_t (&bl)[4]) {
        const unsigned short* bstep = Bfat + (size_t)ks * 4096;
#pragma unroll
        for (int nq = 0; nq < 4; ++nq) {
            bh[nq] = *(const bf16x8_t*)(bstep + ((size_t)(nq * 64 + lane)) * 8);
            bl[nq] = *(const bf16x8_t*)(bstep + ((size_t)((4 + nq) * 64 + lane)) * 8);
        }
    };
    auto compute = [&](const float (&Av)[2][8], float qA, float qB,
                       const bf16x8_t (&bh)[4], const bf16x8_t (&bl)[4]) {
        float pA[8], pB[8];
#pragma unroll
        for (int i = 0; i < 8; ++i) { pA[i] = Av[0][i] * qA; pB[i] = Av[1][i] * qB; }
        bf16x8_t AhiA, AloA, AhiB, AloB;
        split8(pA, AhiA, AloA);
        split8(pB, AhiB, AloB);
#pragma unroll
        for (int nq = 0; nq < 4; ++nq) {
            acc[0][nq] = __builtin_amdgcn_mfma_f32_16x16x32_bf16(AhiA, bh[nq], acc[0][nq], 0, 0, 0);
            acc[0][nq] = __builtin_amdgcn_mfma_f32_16x16x32_bf16(AhiA, bl[nq], acc[0][nq], 0, 0, 0);
            acc[0][nq] = __builtin_amdgcn_mfma_f32_16x16x32_bf16(AloA, bh[nq], acc[0][nq], 0, 0, 0);
            acc[1][nq] = __builtin_amdgcn_mfma_f32_16x16x32_bf16(AhiB, bh[nq], acc[1][nq], 0, 0, 0);
            acc[1][nq] = __builtin_amdgcn_mfma_f32_16x16x32_bf16(AhiB, bl[nq], acc[1][nq], 0, 0, 0);
            acc[1][nq] = __builtin_amdgcn_mfma_f32_16x16x32_bf16(AloB, bh[nq], acc[1][nq], 0, 0, 0);
        }
    };

    // distance-1 software pipeline over parity-unrolled ks loop:
    //   bO(kp+1) issued before even compute; bE(kp+2) issued before odd.
    bf16x8_t bEh[4], bEl[4], bOh[4], bOl[4];
    int kp0 = ks0 & ~1;
    loadB(kp0, bEh, bEl);
    for (int kp = kp0; kp < ks1; kp += 2) {
        bool hasOdd = (kp + 1 < ks1);
        if (hasOdd) loadB(kp + 1, bOh, bOl);
        float qA = 1.f, qB = 1.f;
        if (kp < 128) {
            int qi = (kp >> 1) - q0;
            if (qi >= 0) { qA = ehs[erA][qi]; qB = ehs[erB][qi]; }
        }
        if (kp >= ks0) compute(a0, qA, qB, bEh, bEl);
        if (kp + 2 < ks1) loadB(kp + 2, bEh, bEl);
        if (hasOdd) compute(a1, qA, qB, bOh, bOl);
    }

    // epilogue: plain stores (64B-granular across the 16 lanes of each g-group)
#pragma unroll
    for (int t = 0; t < 2; ++t) {
#pragma unroll
        for (int r = 0; r < 4; ++r) {
            int el = wtile * 32 + t * 16 + g * 4 + r;
            int eg = ebase + el;
            if (eg >= Ee) continue;
            float* mrow = msgbuf + ((size_t)ksplit * Ee + eg) * 64 + m16;
#pragma unroll
            for (int nq = 0; nq < 4; ++nq)
                mrow[nq * 16] = acc[t][nq][r];
        }
    }
}

// Fused GRU: stage m = relu(segsum(msgbuf)/deg + b_conv) and h = out in LDS;
// gates via split-bf16 MFMA (A=[m|h] K=128, N=256); combine in epilogue.
__global__ __launch_bounds__(256) void k_gru_mfma(const float* __restrict__ msgbuf,
                                                  const int* __restrict__ rowptr,
                                                  const float* __restrict__ bconv,
                                                  const unsigned short* __restrict__ Wg,
                                                  const float* __restrict__ bih,
                                                  const float* __restrict__ bhh,
                                                  float* __restrict__ out,
                                                  int nsplit) {
    __shared__ float ms[64][68];
    __shared__ float hs[64][68];
    int tid = threadIdx.x;
    int nbase = blockIdx.x * 64;

    {   // stage: 4 threads per node, 16 cols each; segment-sum msgbuf range
        int nl = tid >> 2, seg = tid & 3;
        int ng = nbase + nl;
        bool v = ng < Nn;
        int p0 = v ? rowptr[ng] : 0;
        int p1 = v ? rowptr[ng + 1] : 0;
        int dg = p1 - p0;
        float rc = 1.f / (float)(dg < 1 ? 1 : dg);
        float s[16];
#pragma unroll
        for (int i = 0; i < 16; ++i) s[i] = 0.f;
        for (int sp = 0; sp < nsplit; ++sp) {
            const float* mb = msgbuf + (size_t)sp * Ee * 64;
            for (int p = p0; p < p1; ++p) {
                const float* mrow = mb + (size_t)p * 64 + seg * 16;
#pragma unroll
                for (int c4 = 0; c4 < 4; ++c4) {
                    float4 t4 = *(const float4*)(mrow + c4 * 4);
                    s[c4 * 4 + 0] += t4.x;
                    s[c4 * 4 + 1] += t4.y;
                    s[c4 * 4 + 2] += t4.z;
                    s[c4 * 4 + 3] += t4.w;
                }
            }
        }
        const float* hrow = out + (size_t)ng * 64 + seg * 16;
        float4 z = make_float4(0.f, 0.f, 0.f, 0.f);
#pragma unroll
        for (int c4 = 0; c4 < 4; ++c4) {
            int col = seg * 16 + c4 * 4;
            float4 hv = v ? *(const float4*)(hrow + c4 * 4) : z;
            ms[nl][col + 0] = fmaxf(s[c4 * 4 + 0] * rc + bconv[col + 0], 0.f);
            ms[nl][col + 1] = fmaxf(s[c4 * 4 + 1] * rc + bconv[col + 1], 0.f);
            ms[nl][col + 2] = fmaxf(s[c4 * 4 + 2] * rc + bconv[col + 2], 0.f);
            ms[nl][col + 3] = fmaxf(s[c4 * 4 + 3] * rc + bconv[col + 3], 0.f);
            *(float4*)&hs[nl][col] = hv;
        }
    }
    __syncthreads();

    int lane = tid & 63;
    int wtile = tid >> 6;
    int m16 = lane & 15;
    int g = lane >> 4;
    int er = wtile * 16 + m16;

    f32x4_t acc[16];
#pragma unroll
    for (int t = 0; t < 16; ++t) acc[t] = (f32x4_t){0.f, 0.f, 0.f, 0.f};

#pragma unroll
    for (int ks = 0; ks < 4; ++ks) {
        const float* src = (ks < 2) ? &ms[er][ks * 32 + g * 8]
                                    : &hs[er][(ks - 2) * 32 + g * 8];
        float p[8];
#pragma unroll
        for (int ii = 0; ii < 8; ++ii) p[ii] = src[ii];
        bf16x8_t Ahi, Alo;
        split8(p, Ahi, Alo);
        const unsigned short* bstep = Wg + (size_t)ks * (2 * 16 * 512);
#pragma unroll
        for (int t = 0; t < 16; ++t) {
            bf16x8_t bhi = *(const bf16x8_t*)(bstep + ((size_t)t * 64 + lane) * 8);
            bf16x8_t blo = *(const bf16x8_t*)(bstep + ((size_t)(16 + t) * 64 + lane) * 8);
            acc[t] = __builtin_amdgcn_mfma_f32_16x16x32_bf16(Ahi, bhi, acc[t], 0, 0, 0);
            acc[t] = __builtin_amdgcn_mfma_f32_16x16x32_bf16(Ahi, blo, acc[t], 0, 0, 0);
            acc[t] = __builtin_amdgcn_mfma_f32_16x16x32_bf16(Alo, bhi, acc[t], 0, 0, 0);
        }
    }

    // epilogue: GRU combine, fully lane-local
#pragma unroll
    for (int t2 = 0; t2 < 4; ++t2) {
        int jj = t2 * 16 + m16;
        float br = bih[jj] + bhh[jj];
        float bz = bih[64 + jj] + bhh[64 + jj];
        float bin_ = bih[128 + jj];
        float bhn = bhh[128 + jj];
#pragma unroll
        for (int r = 0; r < 4; ++r) {
            int nl2 = wtile * 16 + g * 4 + r;
            int ng2 = nbase + nl2;
            if (ng2 >= Nn) continue;
            float rg = sigmoidf_(acc[t2][r] + br);
            float z  = sigmoidf_(acc[4 + t2][r] + bz);
            float nn = tanhf(acc[8 + t2][r] + bin_ + rg * (acc[12 + t2][r] + bhn));
            float hv = hs[nl2][jj];
            out[(size_t)ng2 * 64 + jj] = (1.f - z) * nn + z * hv;
        }
    }
}

// Block-wide reductions (uniform result broadcast to all 256 threads).
__device__ __forceinline__ float block_reduce_max_(float v, float* red, int tid) {
#pragma unroll
    for (int o = 32; o; o >>= 1) v = fmaxf(v, __shfl_xor(v, o, 64));
    if ((tid & 63) == 0) red[tid >> 6] = v;
    __syncthreads();
    float r = fmaxf(fmaxf(red[0], red[1]), fmaxf(red[2], red[3]));
    __syncthreads();
    return r;
}
__device__ __forceinline__ float block_reduce_sum_(float v, float* red, int tid) {
#pragma unroll
    for (int o = 32; o; o >>= 1) v += __shfl_xor(v, o, 64);
    if ((tid & 63) == 0) red[tid >> 6] = v;
    __syncthreads();
    float r = (red[0] + red[1]) + (red[2] + red[3]);
    __syncthreads();
    return r;
}

// Fused Set2Set: one 256-thread block per graph (round 6, validated).
__global__ __launch_bounds__(256) void k_set2set(const float* __restrict__ out,
                                                 const int* __restrict__ bstart,
                                                 const float* __restrict__ Wil,
                                                 const float* __restrict__ bil,
                                                 const float* __restrict__ Whl,
                                                 const float* __restrict__ bhl,
                                                 const float* __restrict__ Wo1,
                                                 const float* __restrict__ bo1,
                                                 const float* __restrict__ Wo2,
                                                 const float* __restrict__ bo2,
                                                 float* __restrict__ outp) {
    __shared__ float qs[128];        // q_star = [q | r]
    __shared__ float hs2[64];        // hl
    __shared__ float cs[64];         // cl
    __shared__ float g_lds[256];     // LSTM gates
    __shared__ float e_lds[S2S_CHUNK];
    __shared__ float red[4];
    __shared__ float rpart[4][64];

    int b = blockIdx.x, tid = threadIdx.x;
    int lane = tid & 63, wv = tid >> 6;
    int s = bstart[b], eend = bstart[b + 1];
    int cntb = eend - s;

    if (tid < 128) qs[tid] = 0.f;
    if (tid < 64) { hs2[tid] = 0.f; cs[tid] = 0.f; }
    __syncthreads();

    for (int step = 0; step < 3; ++step) {
        {
            int u = tid;
            float acc = bil[u] + bhl[u];
            const float4* wi = (const float4*)(Wil + (size_t)u * 128);
#pragma unroll
            for (int k4 = 0; k4 < 32; ++k4) {
                float4 w = wi[k4];
                acc += qs[k4 * 4 + 0] * w.x + qs[k4 * 4 + 1] * w.y +
                       qs[k4 * 4 + 2] * w.z + qs[k4 * 4 + 3] * w.w;
            }
            const float4* wh = (const float4*)(Whl + (size_t)u * 64);
#pragma unroll
            for (int k4 = 0; k4 < 16; ++k4) {
                float4 w = wh[k4];
                acc += hs2[k4 * 4 + 0] * w.x + hs2[k4 * 4 + 1] * w.y +
                       hs2[k4 * 4 + 2] * w.z + hs2[k4 * 4 + 3] * w.w;
            }
            g_lds[u] = acc;
        }
        __syncthreads();
        if (tid < 64) {   // torch order i,f,g,o
            float c = sigmoidf_(g_lds[64 + tid]) * cs[tid] +
                      sigmoidf_(g_lds[tid]) * tanhf(g_lds[128 + tid]);
            cs[tid] = c;
            float h = sigmoidf_(g_lds[192 + tid]) * tanhf(c);
            hs2[tid] = h;
            qs[tid] = h;   // q = hl
        }
        __syncthreads();

        // attention: chunked two-pass softmax, node-parallel
        float gmax = -INFINITY, gsum = 0.f, racc = 0.f;
        for (int c0 = s; c0 < eend; c0 += S2S_CHUNK) {
            int clen = min(S2S_CHUNK, eend - c0);
            for (int i = tid; i < clen; i += 256) {
                const float4* orow = (const float4*)(out + (size_t)(c0 + i) * 64);
                float a0 = 0.f, a1 = 0.f, a2 = 0.f, a3 = 0.f;
#pragma unroll
                for (int k4 = 0; k4 < 16; k4 += 4) {
                    float4 o0 = orow[k4], o1 = orow[k4 + 1], o2 = orow[k4 + 2], o3 = orow[k4 + 3];
                    a0 += o0.x * qs[k4 * 4 + 0]  + o0.y * qs[k4 * 4 + 1]  + o0.z * qs[k4 * 4 + 2]  + o0.w * qs[k4 * 4 + 3];
                    a1 += o1.x * qs[k4 * 4 + 4]  + o1.y * qs[k4 * 4 + 5]  + o1.z * qs[k4 * 4 + 6]  + o1.w * qs[k4 * 4 + 7];
                    a2 += o2.x * qs[k4 * 4 + 8]  + o2.y * qs[k4 * 4 + 9]  + o2.z * qs[k4 * 4 + 10] + o2.w * qs[k4 * 4 + 11];
                    a3 += o3.x * qs[k4 * 4 + 12] + o3.y * qs[k4 * 4 + 13] + o3.z * qs[k4 * 4 + 14] + o3.w * qs[k4 * 4 + 15];
                }
                e_lds[i] = (a0 + a1) + (a2 + a3);
            }
            __syncthreads();
            float m = -INFINITY;
            for (int i = tid; i < clen; i += 256) m = fmaxf(m, e_lds[i]);
            float cmax = block_reduce_max_(m, red, tid);
            float nm = fmaxf(gmax, cmax);
            float scale = expf(gmax - nm);   // 0 on first chunk (gmax=-inf)
            gsum *= scale; racc *= scale;
            float lsum = 0.f;
            for (int i = tid; i < clen; i += 256) {
                float av = expf(e_lds[i] - nm);
                e_lds[i] = av;
                lsum += av;
            }
            gsum += block_reduce_sum_(lsum, red, tid);
            for (int i = wv; i < clen; i += 4)
                racc += e_lds[i] * out[(size_t)(c0 + i) * 64 + lane];
            gmax = nm;
            __syncthreads();
        }
        rpart[wv][lane] = racc;
        __syncthreads();
        if (tid < 64) {
            float r = (rpart[0][tid] + rpart[1][tid]) + (rpart[2][tid] + rpart[3][tid]);
            qs[64 + tid] = (cntb > 0) ? r / gsum : 0.f;
        }
        __syncthreads();
    }

    // final MLP (wave 0)
    if (tid < 64) {
        float acc = bo1[tid];
        const float4* w = (const float4*)(Wo1 + (size_t)tid * 128);
#pragma unroll
        for (int k4 = 0; k4 < 32; ++k4) {
            float4 wv4 = w[k4];
            acc += qs[k4 * 4 + 0] * wv4.x + qs[k4 * 4 + 1] * wv4.y +
                   qs[k4 * 4 + 2] * wv4.z + qs[k4 * 4 + 3] * wv4.w;
        }
        acc = fmaxf(acc, 0.f);
        float t = acc * Wo2[tid];
#pragma unroll
        for (int o = 32; o; o >>= 1) t += __shfl_xor(t, o, 64);
        if (tid == 0) outp[b] = t + bo2[0];
    }
}

extern "C" void kernel_launch(void* const* d_in, const int* in_sizes, int n_in,
                              void* d_out, int out_size, void* d_ws, size_t ws_size,
                              hipStream_t stream) {
    const float* x        = (const float*)d_in[0];
    const float* ea       = (const float*)d_in[1];
    const float* W_in     = (const float*)d_in[2];
    const float* b_in     = (const float*)d_in[3];
    const float* W_e1     = (const float*)d_in[4];
    const float* b_e1     = (const float*)d_in[5];
    const float* W_e2     = (const float*)d_in[6];
    const float* b_e2     = (const float*)d_in[7];
    const float* b_conv   = (const float*)d_in[8];
    const float* W_ih     = (const float*)d_in[9];
    const float* b_ih     = (const float*)d_in[10];
    const float* W_hh     = (const float*)d_in[11];
    const float* b_hh     = (const float*)d_in[12];
    const float* W_ih_l   = (const float*)d_in[13];
    const float* b_ih_l   = (const float*)d_in[14];
    const float* W_hh_l   = (const float*)d_in[15];
    const float* b_hh_l   = (const float*)d_in[16];
    const float* W_o1     = (const float*)d_in[17];
    const float* b_o1     = (const float*)d_in[18];
    const float* W_o2     = (const float*)d_in[19];
    const float* b_o2     = (const float*)d_in[20];
    const int*   ei       = (const int*)d_in[21];
    const int*   batch    = (const int*)d_in[22];
    float* outp = (float*)d_out;

    char* base = (char*)d_ws;
    size_t off = 0;
    auto carve = [&](size_t bytes) -> void* {
        void* p = base + off;
        off = (off + bytes + 255) & ~(size_t)255;
        return p;
    };

    // nsplit = 4
    int ns = 4;
    float *out, *msgbuf, *eh;
    unsigned short *Bfat, *Wg;
    int *srcs, *epos, *rowptr, *wptr, *deg, *bcount, *bstart;
    for (;; ns >>= 1) {
        off = 0;
        out    = (float*)carve((size_t)Nn * 64 * 4);
        msgbuf = (float*)carve((size_t)ns * Ee * 64 * 4);
        eh     = (float*)carve((size_t)Ee * 64 * 4);
        Bfat   = (unsigned short*)carve((size_t)KSTEPS * 4096 * 2);
        Wg     = (unsigned short*)carve((size_t)4 * 2 * 16 * 64 * 8 * 2);
        srcs   = (int*)carve((size_t)Ee * 4);
        epos   = (int*)carve((size_t)Ee * 4);
        rowptr = (int*)carve((size_t)(Nn + 1) * 4);
        wptr   = (int*)carve((size_t)Nn * 4);
        deg    = (int*)carve((size_t)Nn * 4);
        bcount = (int*)carve((size_t)Bb * 4);
        bstart = (int*)carve((size_t)(Bb + 1) * 4);
        if (off <= ws_size || ns == 1) break;
    }
    if (off > ws_size) return;

    hipMemsetAsync(deg, 0, (size_t)Nn * 4, stream);
    hipMemsetAsync(bcount, 0, (size_t)Bb * 4, stream);

    k_fill<<<(FILL_A + FILL_B + FILL_C + FILL_D + 255) / 256, 256, 0, stream>>>(
        x, W_in, b_in, W_e2, b_e2, W_ih, W_hh, ei, batch, out, Bfat, Wg, deg, bcount);
    k_prep_scan<<<2, 256, 0, stream>>>(deg, bcount, rowptr, wptr, bstart);
    k_sort_edges<<<(Ee + 255) / 256, 256, 0, stream>>>(ei, wptr, srcs, epos);
    k_edge_mlp1<<<(Ee * 64) / 256, 256, 0, stream>>>(ea, W_e1, b_e1, epos, eh);

    int eblocks = (Ee + 127) / 128;   // 157
    int nblocks = (Nn + 63) / 64;     // 157
    for (int it = 0; it < 3; ++it) {
        k_msg_mfma<<<dim3(eblocks, ns), 256, 0, stream>>>(out, eh, Bfat, srcs, msgbuf, ns);
        k_gru_mfma<<<nblocks, 256, 0, stream>>>(msgbuf, rowptr, b_conv, Wg, b_ih, b_hh, out, ns);
    }

    k_set2set<<<Bb, 256, 0, stream>>>(out, bstart, W_ih_l, b_ih_l, W_hh_l, b_hh_l,
                                      W_o1, b_o1, W_o2, b_o2, outp);
}